// Round 4
// baseline (114.253 us; speedup 1.0000x reference)
//
#include <hip/hip_runtime.h>
#include <stdint.h>

// inputs [B=64, T=256, D=1024] f32; tanh -> sequential dual-threshold
// integrate-and-fire scan over T per (b,d). 65536 sequences = 1024 waves
// = exactly 1 wave/SIMD (structural). Latency hiding: TRIPLE-buffered
// register pipeline, raw asm loads + manual s_waitcnt vmcnt(N) never
// draining below 16 (AITER-style; compiler-invisible memory ops).
// R4 changes vs R3: prefetch distance 1->2 (wait gets ~2 chunk-times),
// stores drop `nt` (retire into L2 instead of HBM queue -> less vmem
// queue pressure), tanh batch computed before the serial v-chain.
#define B_DIM 64
#define T_STEPS 256
#define D_DIM 1024
#define CT 16                   // timesteps per register chunk
#define CHUNKS (T_STEPS / CT)   // 16
#define TPB 256

// XLA/Eigen f32 tanh rational approximation — bit-exact vs jnp.tanh
// (verified rounds 1-3: absmax = 0.0). DO NOT change the FMA structure.
__device__ __forceinline__ float xla_tanhf(float x) {
    const float kClamp = 7.90531110763549805f;
    float xc = fminf(fmaxf(x, -kClamp), kClamp);
    float x2 = xc * xc;
    float p = __builtin_fmaf(x2, -2.76076847742355e-16f, 2.00018790482477e-13f);
    p = __builtin_fmaf(x2, p, -8.60467152213735e-11f);
    p = __builtin_fmaf(x2, p, 5.12229709037114e-08f);
    p = __builtin_fmaf(x2, p, 1.48572235717979e-05f);
    p = __builtin_fmaf(x2, p, 6.37261928875436e-04f);
    p = __builtin_fmaf(x2, p, 4.89352455891786e-03f);
    p = xc * p;
    float q = __builtin_fmaf(x2, 1.19825839466702e-06f, 1.18534705686654e-04f);
    q = __builtin_fmaf(x2, q, 2.26843463243900e-03f);
    q = __builtin_fmaf(x2, q, 4.89352518554385e-03f);
    float r = p / q;           // IEEE divide — required for bit-exactness
    return (fabsf(x) < 0.0004f) ? x : r;
}

// --- raw-asm pipeline building blocks -----------------------------------
// One load + advance voffi by one timestep (D_DIM*4 = 4096 B; 13-bit imm
// offset can't encode 4096, so explicit v_add). addr = SGPR base + zext(voff).
#define LD(i) "global_load_dword %" #i ", %16, %17\n\t" \
              "v_add_u32 %16, 0x1000, %16\n\t"

#define ISSUE16(Bf) asm volatile( \
    LD(0) LD(1) LD(2) LD(3) LD(4) LD(5) LD(6) LD(7) \
    LD(8) LD(9) LD(10) LD(11) LD(12) LD(13) LD(14) LD(15) \
    : "=v"(Bf[0]), "=v"(Bf[1]), "=v"(Bf[2]), "=v"(Bf[3]), \
      "=v"(Bf[4]), "=v"(Bf[5]), "=v"(Bf[6]), "=v"(Bf[7]), \
      "=v"(Bf[8]), "=v"(Bf[9]), "=v"(Bf[10]), "=v"(Bf[11]), \
      "=v"(Bf[12]), "=v"(Bf[13]), "=v"(Bf[14]), "=v"(Bf[15]), \
      "+v"(voffi) \
    : "s"(inp_u) : "memory")

// Wait until <= CNT vmem ops outstanding; "+v" on the 16 regs of the buffer
// about to be read pins every use after the wait.
#define WAITBUF(Bf, CNT) asm volatile("s_waitcnt vmcnt(" CNT ")" \
    : "+v"(Bf[0]), "+v"(Bf[1]), "+v"(Bf[2]), "+v"(Bf[3]), \
      "+v"(Bf[4]), "+v"(Bf[5]), "+v"(Bf[6]), "+v"(Bf[7]), \
      "+v"(Bf[8]), "+v"(Bf[9]), "+v"(Bf[10]), "+v"(Bf[11]), \
      "+v"(Bf[12]), "+v"(Bf[13]), "+v"(Bf[14]), "+v"(Bf[15]) \
    :: "memory")

// 16 tanh (independent, max ILP) then the 16-step serial v-chain with
// plain cached stores (no nt: retire into L2, don't camp in the HBM queue).
#define COMPUTE16(Bf) do { \
    float rr[CT]; \
    _Pragma("unroll") \
    for (int u = 0; u < CT; ++u) rr[u] = xla_tanhf(Bf[u]); \
    _Pragma("unroll") \
    for (int u = 0; u < CT; ++u) { \
        v = __builtin_fmaf(rr[u], 0.01f, v); \
        float sp = (v >= 1.0f)  ? 1.0f : 0.0f; \
        float sn = (v <= -1.0f) ? 1.0f : 0.0f; \
        v = (v - sp) + sn; \
        float o = (sp - sn) * 100.0f; \
        asm volatile("global_store_dword %0, %1, %2\n\t" \
                     "v_add_u32 %0, 0x1000, %0" \
                     : "+v"(voffo) : "v"(o), "s"(outp_u) : "memory"); \
    } \
} while (0)

// Steady chunk c (computes CUR=L(c), issues L(c+2) into NXT):
// ops newer than L(c) = L(c+1):16 + S(c-1):16 + L(c+2):16 = 48.
#define CHUNK_MID(CUR, NXT) do { ISSUE16(NXT); WAITBUF(CUR, "48"); COMPUTE16(CUR); } while (0)

__global__ __launch_bounds__(TPB)
void spike_scan_kernel(const float* __restrict__ in, float* __restrict__ out) {
    const int gid = blockIdx.x * blockDim.x + threadIdx.x;   // 0..65535
    const int b = gid >> 10;             // / D_DIM
    const int d = gid & (D_DIM - 1);     // % D_DIM
    const uint32_t base_bytes = ((uint32_t)b * (T_STEPS * D_DIM) + (uint32_t)d) * 4u;

    uint32_t voffi = base_bytes;         // running input byte offset (per-lane)
    uint32_t voffo = base_bytes;         // running output byte offset
    const uint64_t inp_u  = (uint64_t)in;
    const uint64_t outp_u = (uint64_t)out;

    float bufA[CT], bufB[CT], bufC[CT];  // L(c) lives in buf[c % 3]
    float v = 0.0f;

    ISSUE16(bufA);                       // L0
    ISSUE16(bufB);                       // L1
    ISSUE16(bufC);                       // L2
    // c=0: newer than L0 = L1+L2 = 32
    WAITBUF(bufA, "32"); COMPUTE16(bufA);
    #pragma unroll 1
    for (int it = 0; it < 4; ++it) {     // chunks 1..12 (period-3 rotation)
        CHUNK_MID(bufB, bufA);           // c=1,4,7,10: compute L(c), issue L(c+2)
        CHUNK_MID(bufC, bufB);           // c=2,5,8,11
        CHUNK_MID(bufA, bufC);           // c=3,6,9,12
    }
    CHUNK_MID(bufB, bufA);               // c=13: issues L15 into bufA
    // c=14: newer than L14 = S13:16 + L15:16 = 32
    WAITBUF(bufC, "32"); COMPUTE16(bufC);
    // c=15: newer than L15 = S14:16
    WAITBUF(bufA, "16"); COMPUTE16(bufA);
}

extern "C" void kernel_launch(void* const* d_in, const int* in_sizes, int n_in,
                              void* d_out, int out_size, void* d_ws, size_t ws_size,
                              hipStream_t stream) {
    const float* in = (const float*)d_in[0];
    float* out = (float*)d_out;
    dim3 block(TPB);
    dim3 grid((B_DIM * D_DIM) / TPB);    // 256 blocks, one 256-thread slice each
    spike_scan_kernel<<<grid, block, 0, stream>>>(in, out);
}